// Round 13
// baseline (501.938 us; speedup 1.0000x reference)
//
#include <hip/hip_runtime.h>
#include <cmath>

#define NN 50000
#define NE 600000
#define NF 128
#define NH 64
#define NC 40

#define SCAN_TPB 512
#define SCAN_NBLK 98  // 98*512 = 50176 >= 50000

#define LDSP2 41

typedef unsigned int uint32;

// f32 -> bf16 with round-to-nearest-even (low 16 bits valid)
static __device__ __forceinline__ uint32 f2bf(float f) {
  uint32 u = __float_as_uint(f);
  uint32 r = 0x7fffu + ((u >> 16) & 1u);
  return (u + r) >> 16;
}
static __device__ __forceinline__ float bf_lo(uint32 u) {
  return __uint_as_float(u << 16);
}
static __device__ __forceinline__ float bf_hi(uint32 u) {
  return __uint_as_float(u & 0xffff0000u);
}

// ---------------- CSR build ----------------
__global__ __launch_bounds__(256) void k_hist(const int* __restrict__ dst,
                                              int* __restrict__ deg) {
  int i0 = blockIdx.x * blockDim.x + threadIdx.x;
  int stride = gridDim.x * blockDim.x;
  for (int e = i0; e < NE; e += stride) atomicAdd(&deg[dst[e]], 1);
}

__global__ __launch_bounds__(SCAN_TPB) void k_scan1(const int* __restrict__ deg,
                                                    int* __restrict__ blocksum) {
  __shared__ int sd[SCAN_TPB];
  int i = blockIdx.x * SCAN_TPB + threadIdx.x;
  sd[threadIdx.x] = (i < NN) ? deg[i] : 0;
  __syncthreads();
  for (int off = SCAN_TPB / 2; off > 0; off >>= 1) {
    if (threadIdx.x < off) sd[threadIdx.x] += sd[threadIdx.x + off];
    __syncthreads();
  }
  if (threadIdx.x == 0) blocksum[blockIdx.x] = sd[0];
}

__global__ __launch_bounds__(128) void k_scan2(const int* __restrict__ blocksum,
                                               int* __restrict__ blockoff) {
  __shared__ int sd[128];
  int tid = threadIdx.x;
  int v = (tid < SCAN_NBLK) ? blocksum[tid] : 0;
  sd[tid] = v;
  __syncthreads();
  for (int off = 1; off < 128; off <<= 1) {
    int t = (tid >= off) ? sd[tid - off] : 0;
    __syncthreads();
    sd[tid] += t;
    __syncthreads();
  }
  if (tid < SCAN_NBLK) blockoff[tid] = sd[tid] - v;  // exclusive
}

__global__ __launch_bounds__(SCAN_TPB) void k_scan3(
    const int* __restrict__ deg, const int* __restrict__ blockoff,
    int* __restrict__ rowptr, int* __restrict__ cursor) {
  __shared__ int sd[SCAN_TPB];
  int tid = threadIdx.x;
  int i = blockIdx.x * SCAN_TPB + tid;
  int v = (i < NN) ? deg[i] : 0;
  sd[tid] = v;
  __syncthreads();
  for (int off = 1; off < SCAN_TPB; off <<= 1) {
    int t = (tid >= off) ? sd[tid - off] : 0;
    __syncthreads();
    sd[tid] += t;
    __syncthreads();
  }
  if (i < NN) {
    int excl = blockoff[blockIdx.x] + sd[tid] - v;
    rowptr[i] = excl;
    cursor[i] = excl;
  }
}

__global__ __launch_bounds__(256) void k_fill(const int* __restrict__ src,
                                              const int* __restrict__ dst,
                                              int* __restrict__ cursor,
                                              int* __restrict__ eid) {
  int i0 = blockIdx.x * blockDim.x + threadIdx.x;
  int stride = gridDim.x * blockDim.x;
  for (int e = i0; e < NE; e += stride) {
    int pos = atomicAdd(&cursor[dst[e]], 1);
    eid[pos] = src[e];
  }
}

// ------- repack: f32 pairs -> bf16x2 u32, fully coalesced streaming -------
__global__ __launch_bounds__(256) void k_repack(const float2* __restrict__ src,
                                                uint32* __restrict__ dst,
                                                int n) {
  int i0 = blockIdx.x * blockDim.x + threadIdx.x;
  int stride = gridDim.x * blockDim.x;
  for (int i = i0; i < n; i += stride) {
    float2 v = src[i];
    dst[i] = f2bf(v.x) | (f2bf(v.y) << 16);
  }
}

// ------- dual proj layer 1: P = x@Wl.T ; Q = x@Wr.T + bl  (128 -> 64) -------
// Weights in LDS as bf16x2 packed along k: swl[kk2*65+o] = {W[o][2kk2],W[o][2kk2+1]}
// 33.3 KB LDS total -> 4 blocks/CU x 8 waves = 8 waves/SIMD; m=4; f32 math.
__global__ __launch_bounds__(512, 8) void k_dual_proj1(
    const float* __restrict__ X, const float* __restrict__ Wl,
    const float* __restrict__ Wr, const float* __restrict__ bl,
    float* __restrict__ P, float* __restrict__ Q) {
  __shared__ uint32 swl[64 * 65];  // 16.6 KB
  __shared__ uint32 swr[64 * 65];
  int tid = threadIdx.x;
  for (int i = tid; i < 64 * 64; i += 512) {
    int kk2 = i & 63, o = i >> 6;  // consecutive tid -> consecutive kk2: coalesced
    float2 vl = *(const float2*)(Wl + o * NF + kk2 * 2);
    float2 vr = *(const float2*)(Wr + o * NF + kk2 * 2);
    swl[kk2 * 65 + o] = f2bf(vl.x) | (f2bf(vl.y) << 16);
    swr[kk2 * 65 + o] = f2bf(vr.x) | (f2bf(vr.y) << 16);
  }
  __syncthreads();
  int lane = tid & 63;
  int wave = blockIdx.x * 8 + (tid >> 6);
  int nw = gridDim.x * 8;
  float blv = bl[lane];
  const int ngroups = NN / 4;  // 12500
  for (int g = wave; g < ngroups; g += nw) {
    int n0 = g * 4;
    const float4* xr = (const float4*)(X + (size_t)n0 * NF);
    float accP[4], accQ[4];
#pragma unroll
    for (int m = 0; m < 4; ++m) { accP[m] = 0.f; accQ[m] = 0.f; }
#pragma unroll 4
    for (int kk = 0; kk < 32; ++kk) {  // 4 k's per step
      uint32 wl01 = swl[(2 * kk) * 65 + lane];
      uint32 wl23 = swl[(2 * kk + 1) * 65 + lane];
      uint32 wr01 = swr[(2 * kk) * 65 + lane];
      uint32 wr23 = swr[(2 * kk + 1) * 65 + lane];
      float l0 = bf_lo(wl01), l1 = bf_hi(wl01), l2 = bf_lo(wl23), l3 = bf_hi(wl23);
      float r0 = bf_lo(wr01), r1 = bf_hi(wr01), r2 = bf_lo(wr23), r3 = bf_hi(wr23);
#pragma unroll
      for (int m = 0; m < 4; ++m) {
        float4 v = xr[m * 32 + kk];  // wave-uniform broadcast
        accP[m] += v.x * l0 + v.y * l1 + v.z * l2 + v.w * l3;
        accQ[m] += v.x * r0 + v.y * r1 + v.z * r2 + v.w * r3;
      }
    }
#pragma unroll
    for (int m = 0; m < 4; ++m) {
      P[(size_t)(n0 + m) * NH + lane] = accP[m];
      Q[(size_t)(n0 + m) * NH + lane] = accQ[m] + blv;
    }
  }
}

// ------- dual proj layer 2 (r7/r10-proven): 256 thr, m=8, f32 outputs --------
__global__ __launch_bounds__(256) void k_dual_proj2(
    const float* __restrict__ H, const float* __restrict__ Wl,
    const float* __restrict__ Wr, const float* __restrict__ bl,
    float* __restrict__ P2, float* __restrict__ Q2) {
  __shared__ float swl[NH * LDSP2 + 64];  // +64 pad: lanes 40..63 read OOB-safe
  __shared__ float swr[NH * LDSP2 + 64];
  int tid = threadIdx.x;
  for (int i = tid; i < NC * NH; i += 256) {
    int j = i >> 6, k = i & 63;
    swl[k * LDSP2 + j] = Wl[i];
    swr[k * LDSP2 + j] = Wr[i];
  }
  __syncthreads();
  int lane = tid & 63;
  int wave = blockIdx.x * 4 + (tid >> 6);
  int nw = gridDim.x * 4;
  float blv = (lane < NC) ? bl[lane] : 0.f;
  const int ngroups = NN / 8;  // 6250
  for (int g = wave; g < ngroups; g += nw) {
    int n0 = g * 8;
    const float4* hr = (const float4*)(H + (size_t)n0 * NH);
    float accP[8], accQ[8];
#pragma unroll
    for (int m = 0; m < 8; ++m) { accP[m] = 0.f; accQ[m] = 0.f; }
#pragma unroll 4
    for (int kk = 0; kk < 16; ++kk) {
      const float* wl4 = &swl[(kk * 4) * LDSP2 + lane];
      const float* wr4 = &swr[(kk * 4) * LDSP2 + lane];
      float l0 = wl4[0], l1 = wl4[LDSP2], l2 = wl4[2 * LDSP2], l3 = wl4[3 * LDSP2];
      float r0 = wr4[0], r1 = wr4[LDSP2], r2 = wr4[2 * LDSP2], r3 = wr4[3 * LDSP2];
#pragma unroll
      for (int m = 0; m < 8; ++m) {
        float4 v = hr[m * 16 + kk];
        accP[m] += v.x * l0 + v.y * l1 + v.z * l2 + v.w * l3;
        accQ[m] += v.x * r0 + v.y * r1 + v.z * r2 + v.w * r3;
      }
    }
    if (lane < NC) {
#pragma unroll
      for (int m = 0; m < 8; ++m) {
        P2[(size_t)(n0 + m) * NC + lane] = accP[m];
        Q2[(size_t)(n0 + m) * NC + lane] = accQ[m] + blv;
      }
    }
  }
}

// ------- gather64: bf16 P, 8 edges/iter, u32 loads (2 ch / 4 B) -------
__global__ __launch_bounds__(256) void k_gather64(
    const uint32* __restrict__ P32, const float* __restrict__ Q,
    const int* __restrict__ rowptr, const int* __restrict__ deg,
    const int* __restrict__ eid, float* __restrict__ H) {
  int lane = threadIdx.x & 63;
  int h = lane >> 5, c2 = lane & 31;
  int wave = blockIdx.x * 4 + (threadIdx.x >> 6);
  int nw = gridDim.x * 4;
  for (int n = wave; n < NN; n += nw) {
    int r0 = rowptr[n], dg = deg[n];
    float ax0 = 0.f, ay0 = 0.f, ax1 = 0.f, ay1 = 0.f;
    for (int base = 0; base < dg; base += 64) {
      int e = dg - base;
      if (e > 64) e = 64;
      int myeid = (lane < e) ? eid[r0 + base + lane] : 0;
      int j = 0;
      for (; j + 8 <= e; j += 8) {
        int sA = __shfl(myeid, j + h);
        int sB = __shfl(myeid, j + 2 + h);
        int sC = __shfl(myeid, j + 4 + h);
        int sD = __shfl(myeid, j + 6 + h);
        uint32 uA = P32[(size_t)sA * (NH / 2) + c2];
        uint32 uB = P32[(size_t)sB * (NH / 2) + c2];
        uint32 uC = P32[(size_t)sC * (NH / 2) + c2];
        uint32 uD = P32[(size_t)sD * (NH / 2) + c2];
        ax0 += __uint_as_float(uA << 16) + __uint_as_float(uC << 16);
        ay0 += __uint_as_float(uA & 0xffff0000u) + __uint_as_float(uC & 0xffff0000u);
        ax1 += __uint_as_float(uB << 16) + __uint_as_float(uD << 16);
        ay1 += __uint_as_float(uB & 0xffff0000u) + __uint_as_float(uD & 0xffff0000u);
      }
      for (; j + 4 <= e; j += 4) {
        int sA = __shfl(myeid, j + h);
        int sB = __shfl(myeid, j + 2 + h);
        uint32 uA = P32[(size_t)sA * (NH / 2) + c2];
        uint32 uB = P32[(size_t)sB * (NH / 2) + c2];
        ax0 += __uint_as_float(uA << 16);
        ay0 += __uint_as_float(uA & 0xffff0000u);
        ax1 += __uint_as_float(uB << 16);
        ay1 += __uint_as_float(uB & 0xffff0000u);
      }
      for (; j < e; j += 2) {
        int sA = __shfl(myeid, j + h);
        if (j + h < e) {
          uint32 uA = P32[(size_t)sA * (NH / 2) + c2];
          ax0 += __uint_as_float(uA << 16);
          ay0 += __uint_as_float(uA & 0xffff0000u);
        }
      }
    }
    float sx = ax0 + ax1, sy = ay0 + ay1;
    sx += __shfl_xor(sx, 32);
    sy += __shfl_xor(sy, 32);
    if (h == 0) {
      float inv = 1.0f / (float)(dg > 0 ? dg : 1);
      float2 qv = *(const float2*)(Q + (size_t)n * NH + 2 * c2);
      float vx = sx * inv + qv.x;
      float vy = sy * inv + qv.y;
      float2 o;
      o.x = 1.0f / (1.0f + __expf(-vx));
      o.y = 1.0f / (1.0f + __expf(-vy));
      *(float2*)(H + (size_t)n * NH + 2 * c2) = o;
    }
  }
}

// ------- gather40: bf16 P2, 8 edges/iter, channel pairs c2<20 -------
__global__ __launch_bounds__(256) void k_gather40(
    const uint32* __restrict__ P2_32, const float* __restrict__ Q2,
    const int* __restrict__ rowptr, const int* __restrict__ deg,
    const int* __restrict__ eid, float* __restrict__ Out) {
  int lane = threadIdx.x & 63;
  int h = lane >> 5, c2 = lane & 31;
  int wave = blockIdx.x * 4 + (threadIdx.x >> 6);
  int nw = gridDim.x * 4;
  for (int n = wave; n < NN; n += nw) {
    int r0 = rowptr[n], dg = deg[n];
    float ax0 = 0.f, ay0 = 0.f, ax1 = 0.f, ay1 = 0.f;
    for (int base = 0; base < dg; base += 64) {
      int e = dg - base;
      if (e > 64) e = 64;
      int myeid = (lane < e) ? eid[r0 + base + lane] : 0;
      int j = 0;
      for (; j + 8 <= e; j += 8) {
        int sA = __shfl(myeid, j + h);
        int sB = __shfl(myeid, j + 2 + h);
        int sC = __shfl(myeid, j + 4 + h);
        int sD = __shfl(myeid, j + 6 + h);
        if (c2 < 20) {
          uint32 uA = P2_32[(size_t)sA * (NC / 2) + c2];
          uint32 uB = P2_32[(size_t)sB * (NC / 2) + c2];
          uint32 uC = P2_32[(size_t)sC * (NC / 2) + c2];
          uint32 uD = P2_32[(size_t)sD * (NC / 2) + c2];
          ax0 += __uint_as_float(uA << 16) + __uint_as_float(uC << 16);
          ay0 += __uint_as_float(uA & 0xffff0000u) + __uint_as_float(uC & 0xffff0000u);
          ax1 += __uint_as_float(uB << 16) + __uint_as_float(uD << 16);
          ay1 += __uint_as_float(uB & 0xffff0000u) + __uint_as_float(uD & 0xffff0000u);
        }
      }
      for (; j + 4 <= e; j += 4) {
        int sA = __shfl(myeid, j + h);
        int sB = __shfl(myeid, j + 2 + h);
        if (c2 < 20) {
          uint32 uA = P2_32[(size_t)sA * (NC / 2) + c2];
          uint32 uB = P2_32[(size_t)sB * (NC / 2) + c2];
          ax0 += __uint_as_float(uA << 16);
          ay0 += __uint_as_float(uA & 0xffff0000u);
          ax1 += __uint_as_float(uB << 16);
          ay1 += __uint_as_float(uB & 0xffff0000u);
        }
      }
      for (; j < e; j += 2) {
        int sA = __shfl(myeid, j + h);
        if (c2 < 20 && (j + h) < e) {
          uint32 uA = P2_32[(size_t)sA * (NC / 2) + c2];
          ax0 += __uint_as_float(uA << 16);
          ay0 += __uint_as_float(uA & 0xffff0000u);
        }
      }
    }
    float sx = ax0 + ax1, sy = ay0 + ay1;
    sx += __shfl_xor(sx, 32);
    sy += __shfl_xor(sy, 32);
    if (h == 0 && c2 < 20) {
      float inv = 1.0f / (float)(dg > 0 ? dg : 1);
      float2 qv = *(const float2*)(Q2 + (size_t)n * NC + 2 * c2);
      float2 o;
      o.x = sx * inv + qv.x;
      o.y = sy * inv + qv.y;
      *(float2*)(Out + (size_t)n * NC + 2 * c2) = o;
    }
  }
}

extern "C" void kernel_launch(void* const* d_in, const int* in_sizes, int n_in,
                              void* d_out, int out_size, void* d_ws,
                              size_t ws_size, hipStream_t stream) {
  const float* x = (const float*)d_in[0];
  const int* ei = (const int*)d_in[1];
  const float* Wl1 = (const float*)d_in[2];
  const float* bl1 = (const float*)d_in[3];
  const float* Wr1 = (const float*)d_in[4];
  const float* Wl2 = (const float*)d_in[5];
  const float* bl2 = (const float*)d_in[6];
  const float* Wr2 = (const float*)d_in[7];
  float* out = (float*)d_out;

  const int* src = ei;       // edge_index[0]
  const int* dst = ei + NE;  // edge_index[1]

  // workspace layout with lifetime-based aliasing (~43 MB):
  //  A: p1f (f32 P1)   -> dead after repack1 -> h lives here
  //  B: p1b (bf16 P1)  -> dead after gather64 -> p2b lives here
  //  C: q1             -> dead after gather64 -> p2f lives here
  //  D: q2             -> live to the end
  char* ws = (char*)d_ws;
  float* p1f = (float*)ws;                                        // A 12.8MB
  uint32* p1b = (uint32*)(ws + (size_t)NN * NH * 4);              // B 6.4MB
  float* q1 = (float*)(ws + (size_t)NN * NH * 6);                 // C 12.8MB
  float* q2 = q1 + (size_t)NN * NH;                               // D 8MB
  int* deg = (int*)(q2 + (size_t)NN * NC);                        // [NN] zeroed
  int* rowptr = deg + NN;
  int* cursor = rowptr + NN;
  int* blocksum = cursor + NN;
  int* blockoff = blocksum + 128;
  int* eid = blockoff + 128;

  float* h = p1f;      // alias A (p1f dead after repack1)
  float* p2f = q1;     // alias C (q1 dead after gather64)
  uint32* p2b = p1b;   // alias B (p1b dead after gather64)

  hipMemsetAsync(deg, 0, NN * sizeof(int), stream);

  // CSR build
  k_hist<<<1024, 256, 0, stream>>>(dst, deg);
  k_scan1<<<SCAN_NBLK, SCAN_TPB, 0, stream>>>(deg, blocksum);
  k_scan2<<<1, 128, 0, stream>>>(blocksum, blockoff);
  k_scan3<<<SCAN_NBLK, SCAN_TPB, 0, stream>>>(deg, blockoff, rowptr, cursor);
  k_fill<<<1024, 256, 0, stream>>>(src, dst, cursor, eid);

  // layer 1
  k_dual_proj1<<<1563, 512, 0, stream>>>(x, Wl1, Wr1, bl1, p1f, q1);
  k_repack<<<1024, 256, 0, stream>>>((const float2*)p1f, p1b, NN * NH / 2);
  k_gather64<<<2048, 256, 0, stream>>>(p1b, q1, rowptr, deg, eid, h);

  // layer 2
  k_dual_proj2<<<1024, 256, 0, stream>>>(h, Wl2, Wr2, bl2, p2f, q2);
  k_repack<<<1024, 256, 0, stream>>>((const float2*)p2f, p2b, NN * NC / 2);
  k_gather40<<<2048, 256, 0, stream>>>(p2b, q2, rowptr, deg, eid, out);
}

// Round 14
// 445.525 us; speedup vs baseline: 1.1266x; 1.1266x over previous
//
#include <hip/hip_runtime.h>
#include <cmath>

#define NN 50000
#define NE 600000
#define NF 128
#define NH 64
#define NC 40

#define SCAN_TPB 512
#define SCAN_NBLK 98  // 98*512 = 50176 >= 50000

#define LDSP2 41

typedef unsigned int uint32;

// f32 -> bf16 with round-to-nearest-even (low 16 bits valid)
static __device__ __forceinline__ uint32 f2bf(float f) {
  uint32 u = __float_as_uint(f);
  uint32 r = 0x7fffu + ((u >> 16) & 1u);
  return (u + r) >> 16;
}
static __device__ __forceinline__ float bf_lo(uint32 u) {
  return __uint_as_float(u << 16);
}
static __device__ __forceinline__ float bf_hi(uint32 u) {
  return __uint_as_float(u & 0xffff0000u);
}

// ---------------- CSR build ----------------
__global__ __launch_bounds__(256) void k_hist(const int* __restrict__ dst,
                                              int* __restrict__ deg) {
  int i0 = blockIdx.x * blockDim.x + threadIdx.x;
  int stride = gridDim.x * blockDim.x;
  for (int e = i0; e < NE; e += stride) atomicAdd(&deg[dst[e]], 1);
}

__global__ __launch_bounds__(SCAN_TPB) void k_scan1(const int* __restrict__ deg,
                                                    int* __restrict__ blocksum) {
  __shared__ int sd[SCAN_TPB];
  int i = blockIdx.x * SCAN_TPB + threadIdx.x;
  sd[threadIdx.x] = (i < NN) ? deg[i] : 0;
  __syncthreads();
  for (int off = SCAN_TPB / 2; off > 0; off >>= 1) {
    if (threadIdx.x < off) sd[threadIdx.x] += sd[threadIdx.x + off];
    __syncthreads();
  }
  if (threadIdx.x == 0) blocksum[blockIdx.x] = sd[0];
}

__global__ __launch_bounds__(128) void k_scan2(const int* __restrict__ blocksum,
                                               int* __restrict__ blockoff) {
  __shared__ int sd[128];
  int tid = threadIdx.x;
  int v = (tid < SCAN_NBLK) ? blocksum[tid] : 0;
  sd[tid] = v;
  __syncthreads();
  for (int off = 1; off < 128; off <<= 1) {
    int t = (tid >= off) ? sd[tid - off] : 0;
    __syncthreads();
    sd[tid] += t;
    __syncthreads();
  }
  if (tid < SCAN_NBLK) blockoff[tid] = sd[tid] - v;  // exclusive
}

__global__ __launch_bounds__(SCAN_TPB) void k_scan3(
    const int* __restrict__ deg, const int* __restrict__ blockoff,
    int* __restrict__ rowptr, int* __restrict__ cursor) {
  __shared__ int sd[SCAN_TPB];
  int tid = threadIdx.x;
  int i = blockIdx.x * SCAN_TPB + tid;
  int v = (i < NN) ? deg[i] : 0;
  sd[tid] = v;
  __syncthreads();
  for (int off = 1; off < SCAN_TPB; off <<= 1) {
    int t = (tid >= off) ? sd[tid - off] : 0;
    __syncthreads();
    sd[tid] += t;
    __syncthreads();
  }
  if (i < NN) {
    int excl = blockoff[blockIdx.x] + sd[tid] - v;
    rowptr[i] = excl;
    cursor[i] = excl;
  }
}

__global__ __launch_bounds__(256) void k_fill(const int* __restrict__ src,
                                              const int* __restrict__ dst,
                                              int* __restrict__ cursor,
                                              int* __restrict__ eid) {
  int i0 = blockIdx.x * blockDim.x + threadIdx.x;
  int stride = gridDim.x * blockDim.x;
  for (int e = i0; e < NE; e += stride) {
    int pos = atomicAdd(&cursor[dst[e]], 1);
    eid[pos] = src[e];
  }
}

// ------- repack: f32 pairs -> bf16x2 u32, fully coalesced streaming -------
__global__ __launch_bounds__(256) void k_repack(const float2* __restrict__ src,
                                                uint32* __restrict__ dst,
                                                int n) {
  int i0 = blockIdx.x * blockDim.x + threadIdx.x;
  int stride = gridDim.x * blockDim.x;
  for (int i = i0; i < n; i += stride) {
    float2 v = src[i];
    dst[i] = f2bf(v.x) | (f2bf(v.y) << 16);
  }
}

// ------- dual proj layer 1: P = x@Wl.T ; Q = x@Wr.T + bl  (128 -> 64) -------
// bf16x2-packed weights in LDS (33.3 KB -> 4 blocks/CU); m=4; f32 math;
// launch_bounds (512,4): VGPR cap 128 -> compiler uses natural ~52-60, NO spill
// (r11: (512,4)+m=8 spilled at VGPR=64; r13: (512,8) forced VGPR=32, spilled).
__global__ __launch_bounds__(512, 4) void k_dual_proj1(
    const float* __restrict__ X, const float* __restrict__ Wl,
    const float* __restrict__ Wr, const float* __restrict__ bl,
    float* __restrict__ P, float* __restrict__ Q) {
  __shared__ uint32 swl[64 * 65];  // 16.6 KB
  __shared__ uint32 swr[64 * 65];
  int tid = threadIdx.x;
  for (int i = tid; i < 64 * 64; i += 512) {
    int kk2 = i & 63, o = i >> 6;  // consecutive tid -> consecutive kk2: coalesced
    float2 vl = *(const float2*)(Wl + o * NF + kk2 * 2);
    float2 vr = *(const float2*)(Wr + o * NF + kk2 * 2);
    swl[kk2 * 65 + o] = f2bf(vl.x) | (f2bf(vl.y) << 16);
    swr[kk2 * 65 + o] = f2bf(vr.x) | (f2bf(vr.y) << 16);
  }
  __syncthreads();
  int lane = tid & 63;
  int wave = blockIdx.x * 8 + (tid >> 6);
  int nw = gridDim.x * 8;
  float blv = bl[lane];
  const int ngroups = NN / 4;  // 12500
  for (int g = wave; g < ngroups; g += nw) {
    int n0 = g * 4;
    const float4* xr = (const float4*)(X + (size_t)n0 * NF);
    float accP[4], accQ[4];
#pragma unroll
    for (int m = 0; m < 4; ++m) { accP[m] = 0.f; accQ[m] = 0.f; }
#pragma unroll 4
    for (int kk = 0; kk < 32; ++kk) {  // 4 k's per step
      uint32 wl01 = swl[(2 * kk) * 65 + lane];
      uint32 wl23 = swl[(2 * kk + 1) * 65 + lane];
      uint32 wr01 = swr[(2 * kk) * 65 + lane];
      uint32 wr23 = swr[(2 * kk + 1) * 65 + lane];
      float l0 = bf_lo(wl01), l1 = bf_hi(wl01), l2 = bf_lo(wl23), l3 = bf_hi(wl23);
      float r0 = bf_lo(wr01), r1 = bf_hi(wr01), r2 = bf_lo(wr23), r3 = bf_hi(wr23);
#pragma unroll
      for (int m = 0; m < 4; ++m) {
        float4 v = xr[m * 32 + kk];  // wave-uniform broadcast
        accP[m] += v.x * l0 + v.y * l1 + v.z * l2 + v.w * l3;
        accQ[m] += v.x * r0 + v.y * r1 + v.z * r2 + v.w * r3;
      }
    }
#pragma unroll
    for (int m = 0; m < 4; ++m) {
      P[(size_t)(n0 + m) * NH + lane] = accP[m];
      Q[(size_t)(n0 + m) * NH + lane] = accQ[m] + blv;
    }
  }
}

// ------- dual proj layer 2 (r7/r10-proven): 256 thr, m=8, f32 outputs --------
__global__ __launch_bounds__(256) void k_dual_proj2(
    const float* __restrict__ H, const float* __restrict__ Wl,
    const float* __restrict__ Wr, const float* __restrict__ bl,
    float* __restrict__ P2, float* __restrict__ Q2) {
  __shared__ float swl[NH * LDSP2 + 64];  // +64 pad: lanes 40..63 read OOB-safe
  __shared__ float swr[NH * LDSP2 + 64];
  int tid = threadIdx.x;
  for (int i = tid; i < NC * NH; i += 256) {
    int j = i >> 6, k = i & 63;
    swl[k * LDSP2 + j] = Wl[i];
    swr[k * LDSP2 + j] = Wr[i];
  }
  __syncthreads();
  int lane = tid & 63;
  int wave = blockIdx.x * 4 + (tid >> 6);
  int nw = gridDim.x * 4;
  float blv = (lane < NC) ? bl[lane] : 0.f;
  const int ngroups = NN / 8;  // 6250
  for (int g = wave; g < ngroups; g += nw) {
    int n0 = g * 8;
    const float4* hr = (const float4*)(H + (size_t)n0 * NH);
    float accP[8], accQ[8];
#pragma unroll
    for (int m = 0; m < 8; ++m) { accP[m] = 0.f; accQ[m] = 0.f; }
#pragma unroll 4
    for (int kk = 0; kk < 16; ++kk) {
      const float* wl4 = &swl[(kk * 4) * LDSP2 + lane];
      const float* wr4 = &swr[(kk * 4) * LDSP2 + lane];
      float l0 = wl4[0], l1 = wl4[LDSP2], l2 = wl4[2 * LDSP2], l3 = wl4[3 * LDSP2];
      float r0 = wr4[0], r1 = wr4[LDSP2], r2 = wr4[2 * LDSP2], r3 = wr4[3 * LDSP2];
#pragma unroll
      for (int m = 0; m < 8; ++m) {
        float4 v = hr[m * 16 + kk];
        accP[m] += v.x * l0 + v.y * l1 + v.z * l2 + v.w * l3;
        accQ[m] += v.x * r0 + v.y * r1 + v.z * r2 + v.w * r3;
      }
    }
    if (lane < NC) {
#pragma unroll
      for (int m = 0; m < 8; ++m) {
        P2[(size_t)(n0 + m) * NC + lane] = accP[m];
        Q2[(size_t)(n0 + m) * NC + lane] = accQ[m] + blv;
      }
    }
  }
}

// ------- gather64: bf16 P, 8 edges/iter, u32 loads (2 ch / 4 B) -------
__global__ __launch_bounds__(256) void k_gather64(
    const uint32* __restrict__ P32, const float* __restrict__ Q,
    const int* __restrict__ rowptr, const int* __restrict__ deg,
    const int* __restrict__ eid, float* __restrict__ H) {
  int lane = threadIdx.x & 63;
  int h = lane >> 5, c2 = lane & 31;
  int wave = blockIdx.x * 4 + (threadIdx.x >> 6);
  int nw = gridDim.x * 4;
  for (int n = wave; n < NN; n += nw) {
    int r0 = rowptr[n], dg = deg[n];
    float ax0 = 0.f, ay0 = 0.f, ax1 = 0.f, ay1 = 0.f;
    for (int base = 0; base < dg; base += 64) {
      int e = dg - base;
      if (e > 64) e = 64;
      int myeid = (lane < e) ? eid[r0 + base + lane] : 0;
      int j = 0;
      for (; j + 8 <= e; j += 8) {
        int sA = __shfl(myeid, j + h);
        int sB = __shfl(myeid, j + 2 + h);
        int sC = __shfl(myeid, j + 4 + h);
        int sD = __shfl(myeid, j + 6 + h);
        uint32 uA = P32[(size_t)sA * (NH / 2) + c2];
        uint32 uB = P32[(size_t)sB * (NH / 2) + c2];
        uint32 uC = P32[(size_t)sC * (NH / 2) + c2];
        uint32 uD = P32[(size_t)sD * (NH / 2) + c2];
        ax0 += __uint_as_float(uA << 16) + __uint_as_float(uC << 16);
        ay0 += __uint_as_float(uA & 0xffff0000u) + __uint_as_float(uC & 0xffff0000u);
        ax1 += __uint_as_float(uB << 16) + __uint_as_float(uD << 16);
        ay1 += __uint_as_float(uB & 0xffff0000u) + __uint_as_float(uD & 0xffff0000u);
      }
      for (; j + 4 <= e; j += 4) {
        int sA = __shfl(myeid, j + h);
        int sB = __shfl(myeid, j + 2 + h);
        uint32 uA = P32[(size_t)sA * (NH / 2) + c2];
        uint32 uB = P32[(size_t)sB * (NH / 2) + c2];
        ax0 += __uint_as_float(uA << 16);
        ay0 += __uint_as_float(uA & 0xffff0000u);
        ax1 += __uint_as_float(uB << 16);
        ay1 += __uint_as_float(uB & 0xffff0000u);
      }
      for (; j < e; j += 2) {
        int sA = __shfl(myeid, j + h);
        if (j + h < e) {
          uint32 uA = P32[(size_t)sA * (NH / 2) + c2];
          ax0 += __uint_as_float(uA << 16);
          ay0 += __uint_as_float(uA & 0xffff0000u);
        }
      }
    }
    float sx = ax0 + ax1, sy = ay0 + ay1;
    sx += __shfl_xor(sx, 32);
    sy += __shfl_xor(sy, 32);
    if (h == 0) {
      float inv = 1.0f / (float)(dg > 0 ? dg : 1);
      float2 qv = *(const float2*)(Q + (size_t)n * NH + 2 * c2);
      float vx = sx * inv + qv.x;
      float vy = sy * inv + qv.y;
      float2 o;
      o.x = 1.0f / (1.0f + __expf(-vx));
      o.y = 1.0f / (1.0f + __expf(-vy));
      *(float2*)(H + (size_t)n * NH + 2 * c2) = o;
    }
  }
}

// ------- gather40: bf16 P2, 8 edges/iter, channel pairs c2<20 -------
__global__ __launch_bounds__(256) void k_gather40(
    const uint32* __restrict__ P2_32, const float* __restrict__ Q2,
    const int* __restrict__ rowptr, const int* __restrict__ deg,
    const int* __restrict__ eid, float* __restrict__ Out) {
  int lane = threadIdx.x & 63;
  int h = lane >> 5, c2 = lane & 31;
  int wave = blockIdx.x * 4 + (threadIdx.x >> 6);
  int nw = gridDim.x * 4;
  for (int n = wave; n < NN; n += nw) {
    int r0 = rowptr[n], dg = deg[n];
    float ax0 = 0.f, ay0 = 0.f, ax1 = 0.f, ay1 = 0.f;
    for (int base = 0; base < dg; base += 64) {
      int e = dg - base;
      if (e > 64) e = 64;
      int myeid = (lane < e) ? eid[r0 + base + lane] : 0;
      int j = 0;
      for (; j + 8 <= e; j += 8) {
        int sA = __shfl(myeid, j + h);
        int sB = __shfl(myeid, j + 2 + h);
        int sC = __shfl(myeid, j + 4 + h);
        int sD = __shfl(myeid, j + 6 + h);
        if (c2 < 20) {
          uint32 uA = P2_32[(size_t)sA * (NC / 2) + c2];
          uint32 uB = P2_32[(size_t)sB * (NC / 2) + c2];
          uint32 uC = P2_32[(size_t)sC * (NC / 2) + c2];
          uint32 uD = P2_32[(size_t)sD * (NC / 2) + c2];
          ax0 += __uint_as_float(uA << 16) + __uint_as_float(uC << 16);
          ay0 += __uint_as_float(uA & 0xffff0000u) + __uint_as_float(uC & 0xffff0000u);
          ax1 += __uint_as_float(uB << 16) + __uint_as_float(uD << 16);
          ay1 += __uint_as_float(uB & 0xffff0000u) + __uint_as_float(uD & 0xffff0000u);
        }
      }
      for (; j + 4 <= e; j += 4) {
        int sA = __shfl(myeid, j + h);
        int sB = __shfl(myeid, j + 2 + h);
        if (c2 < 20) {
          uint32 uA = P2_32[(size_t)sA * (NC / 2) + c2];
          uint32 uB = P2_32[(size_t)sB * (NC / 2) + c2];
          ax0 += __uint_as_float(uA << 16);
          ay0 += __uint_as_float(uA & 0xffff0000u);
          ax1 += __uint_as_float(uB << 16);
          ay1 += __uint_as_float(uB & 0xffff0000u);
        }
      }
      for (; j < e; j += 2) {
        int sA = __shfl(myeid, j + h);
        if (c2 < 20 && (j + h) < e) {
          uint32 uA = P2_32[(size_t)sA * (NC / 2) + c2];
          ax0 += __uint_as_float(uA << 16);
          ay0 += __uint_as_float(uA & 0xffff0000u);
        }
      }
    }
    float sx = ax0 + ax1, sy = ay0 + ay1;
    sx += __shfl_xor(sx, 32);
    sy += __shfl_xor(sy, 32);
    if (h == 0 && c2 < 20) {
      float inv = 1.0f / (float)(dg > 0 ? dg : 1);
      float2 qv = *(const float2*)(Q2 + (size_t)n * NC + 2 * c2);
      float2 o;
      o.x = sx * inv + qv.x;
      o.y = sy * inv + qv.y;
      *(float2*)(Out + (size_t)n * NC + 2 * c2) = o;
    }
  }
}

extern "C" void kernel_launch(void* const* d_in, const int* in_sizes, int n_in,
                              void* d_out, int out_size, void* d_ws,
                              size_t ws_size, hipStream_t stream) {
  const float* x = (const float*)d_in[0];
  const int* ei = (const int*)d_in[1];
  const float* Wl1 = (const float*)d_in[2];
  const float* bl1 = (const float*)d_in[3];
  const float* Wr1 = (const float*)d_in[4];
  const float* Wl2 = (const float*)d_in[5];
  const float* bl2 = (const float*)d_in[6];
  const float* Wr2 = (const float*)d_in[7];
  float* out = (float*)d_out;

  const int* src = ei;       // edge_index[0]
  const int* dst = ei + NE;  // edge_index[1]

  // workspace layout with lifetime-based aliasing (~43 MB):
  //  A: p1f (f32 P1)   -> dead after repack1 -> h lives here
  //  B: p1b (bf16 P1)  -> dead after gather64 -> p2b lives here
  //  C: q1             -> dead after gather64 -> p2f lives here
  //  D: q2             -> live to the end
  char* ws = (char*)d_ws;
  float* p1f = (float*)ws;                                        // A 12.8MB
  uint32* p1b = (uint32*)(ws + (size_t)NN * NH * 4);              // B 6.4MB
  float* q1 = (float*)(ws + (size_t)NN * NH * 6);                 // C 12.8MB
  float* q2 = q1 + (size_t)NN * NH;                               // D 8MB
  int* deg = (int*)(q2 + (size_t)NN * NC);                        // [NN] zeroed
  int* rowptr = deg + NN;
  int* cursor = rowptr + NN;
  int* blocksum = cursor + NN;
  int* blockoff = blocksum + 128;
  int* eid = blockoff + 128;

  float* h = p1f;      // alias A (p1f dead after repack1)
  float* p2f = q1;     // alias C (q1 dead after gather64)
  uint32* p2b = p1b;   // alias B (p1b dead after gather64)

  hipMemsetAsync(deg, 0, NN * sizeof(int), stream);

  // CSR build
  k_hist<<<1024, 256, 0, stream>>>(dst, deg);
  k_scan1<<<SCAN_NBLK, SCAN_TPB, 0, stream>>>(deg, blocksum);
  k_scan2<<<1, 128, 0, stream>>>(blocksum, blockoff);
  k_scan3<<<SCAN_NBLK, SCAN_TPB, 0, stream>>>(deg, blockoff, rowptr, cursor);
  k_fill<<<1024, 256, 0, stream>>>(src, dst, cursor, eid);

  // layer 1
  k_dual_proj1<<<1563, 512, 0, stream>>>(x, Wl1, Wr1, bl1, p1f, q1);
  k_repack<<<1024, 256, 0, stream>>>((const float2*)p1f, p1b, NN * NH / 2);
  k_gather64<<<2048, 256, 0, stream>>>(p1b, q1, rowptr, deg, eid, h);

  // layer 2
  k_dual_proj2<<<1024, 256, 0, stream>>>(h, Wl2, Wr2, bl2, p2f, q2);
  k_repack<<<1024, 256, 0, stream>>>((const float2*)p2f, p2b, NN * NC / 2);
  k_gather40<<<2048, 256, 0, stream>>>(p2b, q2, rowptr, deg, eid, out);
}

// Round 15
// 293.233 us; speedup vs baseline: 1.7117x; 1.5194x over previous
//
#include <hip/hip_runtime.h>
#include <cmath>

#define NN 50000
#define NE 600000
#define NF 128
#define NH 64
#define NC 40

#define SCAN_TPB 512
#define SCAN_NBLK 98  // 98*512 = 50176 >= 50000

#define LDSP1 65  // stride padding: conflict-free stage-write and compute-read
#define LDSP2 41

#define PROJ1_BLOCKS 512
#define HIST_BLOCKS 256

typedef unsigned int uint32;

// f32 -> bf16 with round-to-nearest-even (low 16 bits valid)
static __device__ __forceinline__ uint32 f2bf(float f) {
  uint32 u = __float_as_uint(f);
  uint32 r = 0x7fffu + ((u >> 16) & 1u);
  return (u + r) >> 16;
}

// ---------------- CSR build ----------------
__global__ __launch_bounds__(SCAN_TPB) void k_scan1(const int* __restrict__ deg,
                                                    int* __restrict__ blocksum) {
  __shared__ int sd[SCAN_TPB];
  int i = blockIdx.x * SCAN_TPB + threadIdx.x;
  sd[threadIdx.x] = (i < NN) ? deg[i] : 0;
  __syncthreads();
  for (int off = SCAN_TPB / 2; off > 0; off >>= 1) {
    if (threadIdx.x < off) sd[threadIdx.x] += sd[threadIdx.x + off];
    __syncthreads();
  }
  if (threadIdx.x == 0) blocksum[blockIdx.x] = sd[0];
}

__global__ __launch_bounds__(128) void k_scan2(const int* __restrict__ blocksum,
                                               int* __restrict__ blockoff) {
  __shared__ int sd[128];
  int tid = threadIdx.x;
  int v = (tid < SCAN_NBLK) ? blocksum[tid] : 0;
  sd[tid] = v;
  __syncthreads();
  for (int off = 1; off < 128; off <<= 1) {
    int t = (tid >= off) ? sd[tid - off] : 0;
    __syncthreads();
    sd[tid] += t;
    __syncthreads();
  }
  if (tid < SCAN_NBLK) blockoff[tid] = sd[tid] - v;  // exclusive
}

__global__ __launch_bounds__(SCAN_TPB) void k_scan3(
    const int* __restrict__ deg, const int* __restrict__ blockoff,
    int* __restrict__ rowptr, int* __restrict__ cursor) {
  __shared__ int sd[SCAN_TPB];
  int tid = threadIdx.x;
  int i = blockIdx.x * SCAN_TPB + tid;
  int v = (i < NN) ? deg[i] : 0;
  sd[tid] = v;
  __syncthreads();
  for (int off = 1; off < SCAN_TPB; off <<= 1) {
    int t = (tid >= off) ? sd[tid - off] : 0;
    __syncthreads();
    sd[tid] += t;
    __syncthreads();
  }
  if (i < NN) {
    int excl = blockoff[blockIdx.x] + sd[tid] - v;
    rowptr[i] = excl;
    cursor[i] = excl;
  }
}

__global__ __launch_bounds__(256) void k_fill(const int* __restrict__ src,
                                              const int* __restrict__ dst,
                                              int* __restrict__ cursor,
                                              int* __restrict__ eid) {
  int i0 = blockIdx.x * blockDim.x + threadIdx.x;
  int stride = gridDim.x * blockDim.x;
  for (int e = i0; e < NE; e += stride) {
    int pos = atomicAdd(&cursor[dst[e]], 1);
    eid[pos] = src[e];
  }
}

// ------- repack: f32 pairs -> bf16x2 u32, fully coalesced streaming -------
__global__ __launch_bounds__(256) void k_repack(const float2* __restrict__ src,
                                                uint32* __restrict__ dst,
                                                int n) {
  int i0 = blockIdx.x * blockDim.x + threadIdx.x;
  int stride = gridDim.x * blockDim.x;
  for (int i = i0; i < n; i += stride) {
    float2 v = src[i];
    dst[i] = f2bf(v.x) | (f2bf(v.y) << 16);
  }
}

// ------- dual proj layer 1 (r10-proven) + fused degree histogram -------
// Blocks [0, PROJ1_BLOCKS): P = x@Wl.T ; Q = x@Wr.T + bl (f32 LDS, m=4,
// VGPR~52, no spill). Blocks [PROJ1_BLOCKS, +HIST_BLOCKS): deg histogram
// (block-uniform branch -> no divergent-sync hazard; runs in proj1's shadow).
__global__ __launch_bounds__(512, 4) void k_dual_proj1_hist(
    const float* __restrict__ X, const float* __restrict__ Wl,
    const float* __restrict__ Wr, const float* __restrict__ bl,
    float* __restrict__ P, float* __restrict__ Q,
    const int* __restrict__ dstIdx, int* __restrict__ deg) {
  if (blockIdx.x >= PROJ1_BLOCKS) {
    int i0 = (blockIdx.x - PROJ1_BLOCKS) * 512 + threadIdx.x;
    int stride = HIST_BLOCKS * 512;
    for (int e = i0; e < NE; e += stride) atomicAdd(&deg[dstIdx[e]], 1);
    return;
  }
  __shared__ float swl[NF * LDSP1];
  __shared__ float swr[NF * LDSP1];
  int tid = threadIdx.x;
  for (int i = tid; i < NF * NH; i += 512) {
    int o = i >> 7, k = i & 127;
    swl[k * LDSP1 + o] = Wl[i];  // write banks stride 1 mod 32: conflict-free
    swr[k * LDSP1 + o] = Wr[i];
  }
  __syncthreads();
  int lane = tid & 63;
  int wave = blockIdx.x * 8 + (tid >> 6);
  int nw = PROJ1_BLOCKS * 8;
  float blv = bl[lane];
  const int ngroups = NN / 4;  // 12500 exactly
  for (int g = wave; g < ngroups; g += nw) {
    int n0 = g * 4;
    const float4* xr = (const float4*)(X + (size_t)n0 * NF);
    float accP[4], accQ[4];
#pragma unroll
    for (int m = 0; m < 4; ++m) { accP[m] = 0.f; accQ[m] = 0.f; }
#pragma unroll 4
    for (int kk = 0; kk < 32; ++kk) {
      const float* wl4 = &swl[(kk * 4) * LDSP1 + lane];
      const float* wr4 = &swr[(kk * 4) * LDSP1 + lane];
      float l0 = wl4[0], l1 = wl4[LDSP1], l2 = wl4[2 * LDSP1], l3 = wl4[3 * LDSP1];
      float r0 = wr4[0], r1 = wr4[LDSP1], r2 = wr4[2 * LDSP1], r3 = wr4[3 * LDSP1];
#pragma unroll
      for (int m = 0; m < 4; ++m) {
        float4 v = xr[m * 32 + kk];  // wave-uniform broadcast
        accP[m] += v.x * l0 + v.y * l1 + v.z * l2 + v.w * l3;
        accQ[m] += v.x * r0 + v.y * r1 + v.z * r2 + v.w * r3;
      }
    }
#pragma unroll
    for (int m = 0; m < 4; ++m) {
      P[(size_t)(n0 + m) * NH + lane] = accP[m];
      Q[(size_t)(n0 + m) * NH + lane] = accQ[m] + blv;
    }
  }
}

// ------- dual proj layer 2 (r7/r10-proven): 256 thr, m=8, f32 outputs --------
__global__ __launch_bounds__(256) void k_dual_proj2(
    const float* __restrict__ H, const float* __restrict__ Wl,
    const float* __restrict__ Wr, const float* __restrict__ bl,
    float* __restrict__ P2, float* __restrict__ Q2) {
  __shared__ float swl[NH * LDSP2 + 64];  // +64 pad: lanes 40..63 read OOB-safe
  __shared__ float swr[NH * LDSP2 + 64];
  int tid = threadIdx.x;
  for (int i = tid; i < NC * NH; i += 256) {
    int j = i >> 6, k = i & 63;
    swl[k * LDSP2 + j] = Wl[i];
    swr[k * LDSP2 + j] = Wr[i];
  }
  __syncthreads();
  int lane = tid & 63;
  int wave = blockIdx.x * 4 + (tid >> 6);
  int nw = gridDim.x * 4;
  float blv = (lane < NC) ? bl[lane] : 0.f;
  const int ngroups = NN / 8;  // 6250
  for (int g = wave; g < ngroups; g += nw) {
    int n0 = g * 8;
    const float4* hr = (const float4*)(H + (size_t)n0 * NH);
    float accP[8], accQ[8];
#pragma unroll
    for (int m = 0; m < 8; ++m) { accP[m] = 0.f; accQ[m] = 0.f; }
#pragma unroll 4
    for (int kk = 0; kk < 16; ++kk) {
      const float* wl4 = &swl[(kk * 4) * LDSP2 + lane];
      const float* wr4 = &swr[(kk * 4) * LDSP2 + lane];
      float l0 = wl4[0], l1 = wl4[LDSP2], l2 = wl4[2 * LDSP2], l3 = wl4[3 * LDSP2];
      float r0 = wr4[0], r1 = wr4[LDSP2], r2 = wr4[2 * LDSP2], r3 = wr4[3 * LDSP2];
#pragma unroll
      for (int m = 0; m < 8; ++m) {
        float4 v = hr[m * 16 + kk];
        accP[m] += v.x * l0 + v.y * l1 + v.z * l2 + v.w * l3;
        accQ[m] += v.x * r0 + v.y * r1 + v.z * r2 + v.w * r3;
      }
    }
    if (lane < NC) {
#pragma unroll
      for (int m = 0; m < 8; ++m) {
        P2[(size_t)(n0 + m) * NC + lane] = accP[m];
        Q2[(size_t)(n0 + m) * NC + lane] = accQ[m] + blv;
      }
    }
  }
}

// ------- gather64: bf16 P, 8 edges/iter, u32 loads (2 ch / 4 B) -------
__global__ __launch_bounds__(256) void k_gather64(
    const uint32* __restrict__ P32, const float* __restrict__ Q,
    const int* __restrict__ rowptr, const int* __restrict__ deg,
    const int* __restrict__ eid, float* __restrict__ H) {
  int lane = threadIdx.x & 63;
  int h = lane >> 5, c2 = lane & 31;
  int wave = blockIdx.x * 4 + (threadIdx.x >> 6);
  int nw = gridDim.x * 4;
  for (int n = wave; n < NN; n += nw) {
    int r0 = rowptr[n], dg = deg[n];
    float ax0 = 0.f, ay0 = 0.f, ax1 = 0.f, ay1 = 0.f;
    for (int base = 0; base < dg; base += 64) {
      int e = dg - base;
      if (e > 64) e = 64;
      int myeid = (lane < e) ? eid[r0 + base + lane] : 0;
      int j = 0;
      for (; j + 8 <= e; j += 8) {
        int sA = __shfl(myeid, j + h);
        int sB = __shfl(myeid, j + 2 + h);
        int sC = __shfl(myeid, j + 4 + h);
        int sD = __shfl(myeid, j + 6 + h);
        uint32 uA = P32[(size_t)sA * (NH / 2) + c2];
        uint32 uB = P32[(size_t)sB * (NH / 2) + c2];
        uint32 uC = P32[(size_t)sC * (NH / 2) + c2];
        uint32 uD = P32[(size_t)sD * (NH / 2) + c2];
        ax0 += __uint_as_float(uA << 16) + __uint_as_float(uC << 16);
        ay0 += __uint_as_float(uA & 0xffff0000u) + __uint_as_float(uC & 0xffff0000u);
        ax1 += __uint_as_float(uB << 16) + __uint_as_float(uD << 16);
        ay1 += __uint_as_float(uB & 0xffff0000u) + __uint_as_float(uD & 0xffff0000u);
      }
      for (; j + 4 <= e; j += 4) {
        int sA = __shfl(myeid, j + h);
        int sB = __shfl(myeid, j + 2 + h);
        uint32 uA = P32[(size_t)sA * (NH / 2) + c2];
        uint32 uB = P32[(size_t)sB * (NH / 2) + c2];
        ax0 += __uint_as_float(uA << 16);
        ay0 += __uint_as_float(uA & 0xffff0000u);
        ax1 += __uint_as_float(uB << 16);
        ay1 += __uint_as_float(uB & 0xffff0000u);
      }
      for (; j < e; j += 2) {
        int sA = __shfl(myeid, j + h);
        if (j + h < e) {
          uint32 uA = P32[(size_t)sA * (NH / 2) + c2];
          ax0 += __uint_as_float(uA << 16);
          ay0 += __uint_as_float(uA & 0xffff0000u);
        }
      }
    }
    float sx = ax0 + ax1, sy = ay0 + ay1;
    sx += __shfl_xor(sx, 32);
    sy += __shfl_xor(sy, 32);
    if (h == 0) {
      float inv = 1.0f / (float)(dg > 0 ? dg : 1);
      float2 qv = *(const float2*)(Q + (size_t)n * NH + 2 * c2);
      float vx = sx * inv + qv.x;
      float vy = sy * inv + qv.y;
      float2 o;
      o.x = 1.0f / (1.0f + __expf(-vx));
      o.y = 1.0f / (1.0f + __expf(-vy));
      *(float2*)(H + (size_t)n * NH + 2 * c2) = o;
    }
  }
}

// ------- gather40: bf16 P2, 8 edges/iter, channel pairs c2<20 -------
__global__ __launch_bounds__(256) void k_gather40(
    const uint32* __restrict__ P2_32, const float* __restrict__ Q2,
    const int* __restrict__ rowptr, const int* __restrict__ deg,
    const int* __restrict__ eid, float* __restrict__ Out) {
  int lane = threadIdx.x & 63;
  int h = lane >> 5, c2 = lane & 31;
  int wave = blockIdx.x * 4 + (threadIdx.x >> 6);
  int nw = gridDim.x * 4;
  for (int n = wave; n < NN; n += nw) {
    int r0 = rowptr[n], dg = deg[n];
    float ax0 = 0.f, ay0 = 0.f, ax1 = 0.f, ay1 = 0.f;
    for (int base = 0; base < dg; base += 64) {
      int e = dg - base;
      if (e > 64) e = 64;
      int myeid = (lane < e) ? eid[r0 + base + lane] : 0;
      int j = 0;
      for (; j + 8 <= e; j += 8) {
        int sA = __shfl(myeid, j + h);
        int sB = __shfl(myeid, j + 2 + h);
        int sC = __shfl(myeid, j + 4 + h);
        int sD = __shfl(myeid, j + 6 + h);
        if (c2 < 20) {
          uint32 uA = P2_32[(size_t)sA * (NC / 2) + c2];
          uint32 uB = P2_32[(size_t)sB * (NC / 2) + c2];
          uint32 uC = P2_32[(size_t)sC * (NC / 2) + c2];
          uint32 uD = P2_32[(size_t)sD * (NC / 2) + c2];
          ax0 += __uint_as_float(uA << 16) + __uint_as_float(uC << 16);
          ay0 += __uint_as_float(uA & 0xffff0000u) + __uint_as_float(uC & 0xffff0000u);
          ax1 += __uint_as_float(uB << 16) + __uint_as_float(uD << 16);
          ay1 += __uint_as_float(uB & 0xffff0000u) + __uint_as_float(uD & 0xffff0000u);
        }
      }
      for (; j + 4 <= e; j += 4) {
        int sA = __shfl(myeid, j + h);
        int sB = __shfl(myeid, j + 2 + h);
        if (c2 < 20) {
          uint32 uA = P2_32[(size_t)sA * (NC / 2) + c2];
          uint32 uB = P2_32[(size_t)sB * (NC / 2) + c2];
          ax0 += __uint_as_float(uA << 16);
          ay0 += __uint_as_float(uA & 0xffff0000u);
          ax1 += __uint_as_float(uB << 16);
          ay1 += __uint_as_float(uB & 0xffff0000u);
        }
      }
      for (; j < e; j += 2) {
        int sA = __shfl(myeid, j + h);
        if (c2 < 20 && (j + h) < e) {
          uint32 uA = P2_32[(size_t)sA * (NC / 2) + c2];
          ax0 += __uint_as_float(uA << 16);
          ay0 += __uint_as_float(uA & 0xffff0000u);
        }
      }
    }
    float sx = ax0 + ax1, sy = ay0 + ay1;
    sx += __shfl_xor(sx, 32);
    sy += __shfl_xor(sy, 32);
    if (h == 0 && c2 < 20) {
      float inv = 1.0f / (float)(dg > 0 ? dg : 1);
      float2 qv = *(const float2*)(Q2 + (size_t)n * NC + 2 * c2);
      float2 o;
      o.x = sx * inv + qv.x;
      o.y = sy * inv + qv.y;
      *(float2*)(Out + (size_t)n * NC + 2 * c2) = o;
    }
  }
}

extern "C" void kernel_launch(void* const* d_in, const int* in_sizes, int n_in,
                              void* d_out, int out_size, void* d_ws,
                              size_t ws_size, hipStream_t stream) {
  const float* x = (const float*)d_in[0];
  const int* ei = (const int*)d_in[1];
  const float* Wl1 = (const float*)d_in[2];
  const float* bl1 = (const float*)d_in[3];
  const float* Wr1 = (const float*)d_in[4];
  const float* Wl2 = (const float*)d_in[5];
  const float* bl2 = (const float*)d_in[6];
  const float* Wr2 = (const float*)d_in[7];
  float* out = (float*)d_out;

  const int* src = ei;       // edge_index[0]
  const int* dst = ei + NE;  // edge_index[1]

  // workspace layout with lifetime-based aliasing (~43 MB):
  //  A: p1f (f32 P1)   -> dead after repack1 -> h lives here
  //  B: p1b (bf16 P1)  -> dead after gather64 -> p2b lives here
  //  C: q1             -> dead after gather64 -> p2f lives here
  //  D: q2             -> live to the end
  char* ws = (char*)d_ws;
  float* p1f = (float*)ws;                                        // A 12.8MB
  uint32* p1b = (uint32*)(ws + (size_t)NN * NH * 4);              // B 6.4MB
  float* q1 = (float*)(ws + (size_t)NN * NH * 6);                 // C 12.8MB
  float* q2 = q1 + (size_t)NN * NH;                               // D 8MB
  int* deg = (int*)(q2 + (size_t)NN * NC);                        // [NN] zeroed
  int* rowptr = deg + NN;
  int* cursor = rowptr + NN;
  int* blocksum = cursor + NN;
  int* blockoff = blocksum + 128;
  int* eid = blockoff + 128;

  float* h = p1f;      // alias A (p1f dead after repack1)
  float* p2f = q1;     // alias C (q1 dead after gather64)
  uint32* p2b = p1b;   // alias B (p1b dead after gather64)

  hipMemsetAsync(deg, 0, NN * sizeof(int), stream);

  // layer-1 projection with fused degree histogram (hist runs in its shadow)
  k_dual_proj1_hist<<<PROJ1_BLOCKS + HIST_BLOCKS, 512, 0, stream>>>(
      x, Wl1, Wr1, bl1, p1f, q1, dst, deg);

  // CSR build (scan depends on hist; fill depends on scan)
  k_scan1<<<SCAN_NBLK, SCAN_TPB, 0, stream>>>(deg, blocksum);
  k_scan2<<<1, 128, 0, stream>>>(blocksum, blockoff);
  k_scan3<<<SCAN_NBLK, SCAN_TPB, 0, stream>>>(deg, blockoff, rowptr, cursor);
  k_fill<<<1024, 256, 0, stream>>>(src, dst, cursor, eid);

  // layer 1 gather
  k_repack<<<1024, 256, 0, stream>>>((const float2*)p1f, p1b, NN * NH / 2);
  k_gather64<<<2048, 256, 0, stream>>>(p1b, q1, rowptr, deg, eid, h);

  // layer 2
  k_dual_proj2<<<1563, 256, 0, stream>>>(h, Wl2, Wr2, bl2, p2f, q2);
  k_repack<<<1024, 256, 0, stream>>>((const float2*)p2f, p2b, NN * NC / 2);
  k_gather40<<<2048, 256, 0, stream>>>(p2b, q2, rowptr, deg, eid, out);
}